// Round 12
// baseline (352.955 us; speedup 1.0000x reference)
//
#include <hip/hip_runtime.h>
#include <hip/hip_bf16.h>

// CosineSelfAttention — bf16 MFMA version, v4.
// B=4, S=4096, DM=1024, H=16, D=64. Linear attention.
//
// v4 changes:
//   * gemm_qkv epilogue now applies mask AND cosine row-normalization for
//     Q and K (4x shfl_xor over 16-lane group + rsqrt) -> qkv holds Qn/Kn/V
//   * attnA: pure transpose + MFMA + sums (no mask/norm)
//   * attnB: no mask/norm (Qn pre-normalized)
//   * reduceKV: re-gridded (16 x 64) = 1024 blocks, coalesced

#define B_  4
#define S_  4096
#define DM_ 1024
#define H_  16
#define D_  64
#define EPSF 1e-5f
#define NT_ 32   // 128-row s-tiles per (b,h) in attnA
#define BKG 64   // gemm k-step

typedef __attribute__((ext_vector_type(8))) short short8;
typedef __attribute__((ext_vector_type(4))) float f32x4;

__device__ inline unsigned short f32_to_bf16(float f) {
    unsigned int u = __builtin_bit_cast(unsigned int, f);
    u = (u + 0x7FFFu + ((u >> 16) & 1u)) >> 16;   // RNE
    return (unsigned short)u;
}
__device__ inline float bf16_to_f32(unsigned short u) {
    return __builtin_bit_cast(float, (unsigned int)u << 16);
}

__global__ __launch_bounds__(256)
void msum_kernel(const float* __restrict__ mask, float* __restrict__ msum) {
    const int b = blockIdx.x;
    float s = 0.f;
    for (int i = threadIdx.x; i < S_; i += 256)
        s += mask[b * S_ + i] / 10000.0f + 1.0f;
    for (int off = 32; off > 0; off >>= 1) s += __shfl_down(s, off);
    __shared__ float tmp[4];
    if ((threadIdx.x & 63) == 0) tmp[threadIdx.x >> 6] = s;
    __syncthreads();
    if (threadIdx.x == 0) msum[b] = tmp[0] + tmp[1] + tmp[2] + tmp[3];
}

// ---- hidden f32 -> bf16 ----------------------------------------------------
__global__ __launch_bounds__(256)
void convH(const float* __restrict__ h, unsigned short* __restrict__ hb) {
    const size_t i = ((size_t)blockIdx.x * 256 + threadIdx.x) * 8;
    const float4 a = *reinterpret_cast<const float4*>(h + i);
    const float4 c = *reinterpret_cast<const float4*>(h + i + 4);
    uint4 pk;
    pk.x = (unsigned int)f32_to_bf16(a.x) | ((unsigned int)f32_to_bf16(a.y) << 16);
    pk.y = (unsigned int)f32_to_bf16(a.z) | ((unsigned int)f32_to_bf16(a.w) << 16);
    pk.z = (unsigned int)f32_to_bf16(c.x) | ((unsigned int)f32_to_bf16(c.y) << 16);
    pk.w = (unsigned int)f32_to_bf16(c.z) | ((unsigned int)f32_to_bf16(c.w) << 16);
    *reinterpret_cast<uint4*>(hb + i) = pk;
}

// ---- Wt[n][k] = bf16(W[k][n]), per 64x64 tile ------------------------------
__global__ __launch_bounds__(256)
void transposeW(const float* __restrict__ Wq, const float* __restrict__ Wk,
                const float* __restrict__ Wv, unsigned short* __restrict__ Wt)
{
    __shared__ float T2[64 * 65];   // [nc][kr]
    const int tid = threadIdx.x;
    const int k0 = blockIdx.x * 64, n0 = blockIdx.y * 64, mi = blockIdx.z;
    const float* W = (mi == 0) ? Wq : (mi == 1) ? Wk : Wv;

#pragma unroll
    for (int t = 0; t < 4; ++t) {
        const int idx = t * 256 + tid;
        const int kr = idx >> 4, nc4 = idx & 15;
        const float4 v = *reinterpret_cast<const float4*>(
            &W[(size_t)(k0 + kr) * DM_ + n0 + nc4 * 4]);
        T2[(nc4 * 4 + 0) * 65 + kr] = v.x;
        T2[(nc4 * 4 + 1) * 65 + kr] = v.y;
        T2[(nc4 * 4 + 2) * 65 + kr] = v.z;
        T2[(nc4 * 4 + 3) * 65 + kr] = v.w;
    }
    __syncthreads();
#pragma unroll
    for (int t = 0; t < 4; ++t) {
        const int idx = t * 256 + tid;
        const int nr = idx >> 4, kc4 = idx & 15;
        unsigned int p0 = (unsigned int)f32_to_bf16(T2[nr * 65 + kc4 * 4 + 0]) |
                          ((unsigned int)f32_to_bf16(T2[nr * 65 + kc4 * 4 + 1]) << 16);
        unsigned int p1 = (unsigned int)f32_to_bf16(T2[nr * 65 + kc4 * 4 + 2]) |
                          ((unsigned int)f32_to_bf16(T2[nr * 65 + kc4 * 4 + 3]) << 16);
        uint2 pk; pk.x = p0; pk.y = p1;
        *reinterpret_cast<uint2*>(
            &Wt[(size_t)mi * DM_ * DM_ + (size_t)(n0 + nr) * DM_ + k0 + kc4 * 4]) = pk;
    }
}

// ---- qkv = {Qn, Kn, V}: GEMM + bias (+ mask + cosine-norm for Q,K) --------
__global__ __launch_bounds__(256)
void gemm_qkv(const unsigned short* __restrict__ hb, const unsigned short* __restrict__ Wt,
              const float* __restrict__ bq, const float* __restrict__ bk,
              const float* __restrict__ bv, const float* __restrict__ mask,
              unsigned short* __restrict__ qkv)
{
    __shared__ __align__(16) unsigned short As[128 * BKG];
    __shared__ __align__(16) unsigned short Bs[128 * BKG];

    const int tid = threadIdx.x;
    const int lane = tid & 63, w = tid >> 6;
    const int lx = lane & 15, gk = lane >> 4;
    const int wr = w >> 1, wc = w & 1;

    // T1: bijective XCD swizzle. 3072 blocks, 8 XCDs -> 384 contiguous each.
    const int wg = blockIdx.x;
    const int swz = (wg & 7) * 384 + (wg >> 3);
    const int mi = swz >> 10;            // 0..2
    const int rem = swz & 1023;
    const int mbase = (rem >> 3) * 128;
    const int nbase = (rem & 7) * 128;

    const float* bias = (mi == 0) ? bq : (mi == 1) ? bk : bv;
    const unsigned short* Wm = Wt + (size_t)mi * DM_ * DM_;
    unsigned short* outm = qkv + (size_t)mi * (B_ * S_) * DM_;

    const int srow = w * 32 + (lane >> 3);
    const int sslot = (lane & 7) ^ (lane >> 3);
    const unsigned short* aSrc = hb + (size_t)(mbase + srow) * DM_ + sslot * 8;
    const unsigned short* bSrc = Wm + (size_t)(nbase + srow) * DM_ + sslot * 8;

    f32x4 acc[4][4] = {};

    for (int kt = 0; kt < DM_ / BKG; ++kt) {
#pragma unroll
        for (int t = 0; t < 4; ++t) {
            __builtin_amdgcn_global_load_lds(
                (const __attribute__((address_space(1))) unsigned int*)(aSrc + kt * BKG + (size_t)t * 8 * DM_),
                (__attribute__((address_space(3))) unsigned int*)&As[(w * 32 + t * 8) * BKG],
                16, 0, 0);
            __builtin_amdgcn_global_load_lds(
                (const __attribute__((address_space(1))) unsigned int*)(bSrc + kt * BKG + (size_t)t * 8 * DM_),
                (__attribute__((address_space(3))) unsigned int*)&Bs[(w * 32 + t * 8) * BKG],
                16, 0, 0);
        }
        __syncthreads();

#pragma unroll
        for (int ks = 0; ks < 2; ++ks) {
            short8 a[4], bb[4];
#pragma unroll
            for (int f = 0; f < 4; ++f) {
                const int row = wr * 64 + f * 16 + lx;
                a[f] = *reinterpret_cast<const short8*>(
                    &As[row * BKG + (((ks * 4 + gk) ^ (lx & 7)) * 8)]);
            }
#pragma unroll
            for (int n = 0; n < 4; ++n) {
                const int row = wc * 64 + n * 16 + lx;
                bb[n] = *reinterpret_cast<const short8*>(
                    &Bs[row * BKG + (((ks * 4 + gk) ^ (lx & 7)) * 8)]);
            }
#pragma unroll
            for (int f = 0; f < 4; ++f)
#pragma unroll
                for (int n = 0; n < 4; ++n)
                    acc[f][n] = __builtin_amdgcn_mfma_f32_16x16x32_bf16(a[f], bb[n], acc[f][n], 0, 0, 0);
        }
        __syncthreads();
    }

    // epilogue: +bias; Q,K: *mask then row-normalize (row = 64 cols = wc half,
    // spread over 16 lanes (lx) x 4 n-frags -> 4x shfl_xor reduce); -> bf16
    const int cole = nbase + wc * 64;
    float bias4[4];
#pragma unroll
    for (int n = 0; n < 4; ++n) bias4[n] = bias[cole + n * 16 + lx];

#pragma unroll
    for (int f = 0; f < 4; ++f) {
        const int rbase = mbase + wr * 64 + f * 16 + gk * 4;
        float y[4][4];
#pragma unroll
        for (int reg = 0; reg < 4; ++reg) {
            const float m = (mi == 2) ? 1.0f : (mask[rbase + reg] / 10000.0f + 1.0f);
            float ss = 0.f;
#pragma unroll
            for (int n = 0; n < 4; ++n) {
                const float v = (acc[f][n][reg] + bias4[n]) * m;
                y[reg][n] = v;
                ss += v * v;
            }
            if (mi != 2) {
                ss += __shfl_xor(ss, 1);
                ss += __shfl_xor(ss, 2);
                ss += __shfl_xor(ss, 4);
                ss += __shfl_xor(ss, 8);
                const float inv = 1.0f / (sqrtf(ss) + EPSF);
#pragma unroll
                for (int n = 0; n < 4; ++n) y[reg][n] *= inv;
            }
        }
#pragma unroll
        for (int n = 0; n < 4; ++n)
#pragma unroll
            for (int reg = 0; reg < 4; ++reg)
                outm[(size_t)(rbase + reg) * DM_ + cole + n * 16 + lx] =
                    f32_to_bf16(y[reg][n]);
    }
}

// ---- attnA: per (b,h,128-row tile): transpose -> kv += Kn^T V, sums --------
__global__ __launch_bounds__(256)
void attnA(const unsigned short* __restrict__ qkv,
           float* __restrict__ kvpart, float* __restrict__ kspart,
           float* __restrict__ vspart)
{
    __shared__ unsigned short KnT[64 * 136];  // [d][r], stride 136
    __shared__ unsigned short VT[64 * 136];   // [e][r]

    const int tid = threadIdx.x;
    const int lane = tid & 63, w = tid >> 6;
    const int lx = lane & 15, gk = lane >> 4;
    const int stile = blockIdx.x, h = blockIdx.y, b = blockIdx.z;
    const int col0 = h * D_;
    const int s0 = stile * 128;
    const int bh = b * H_ + h;

    const int rr = tid & 127;      // row within tile
    const int isV = tid >> 7;      // waves 0-1: Kn rows, waves 2-3: V rows
    const int srow = s0 + rr;

    const unsigned short* grow = qkv + (size_t)(1 + isV) * (B_ * S_) * DM_ +
                                 (size_t)(b * S_ + srow) * DM_ + col0;
    unsigned short* dst = isV ? VT : KnT;

    {
        short8 r8[8];
#pragma unroll
        for (int v = 0; v < 8; ++v)
            r8[v] = *reinterpret_cast<const short8*>(grow + v * 8);
#pragma unroll
        for (int v = 0; v < 8; ++v)
#pragma unroll
            for (int j = 0; j < 8; ++j)
                dst[(v * 8 + j) * 136 + rr] = (unsigned short)r8[v][j];
    }
    __syncthreads();

    f32x4 kvacc[4] = {};
#pragma unroll
    for (int kk = 0; kk < 4; ++kk) {
        const short8 af = *reinterpret_cast<const short8*>(
            &KnT[(w * 16 + lx) * 136 + kk * 32 + gk * 8]);
#pragma unroll
        for (int nb = 0; nb < 4; ++nb) {
            const short8 bf = *reinterpret_cast<const short8*>(
                &VT[(nb * 16 + lx) * 136 + kk * 32 + gk * 8]);
            kvacc[nb] = __builtin_amdgcn_mfma_f32_16x16x32_bf16(af, bf, kvacc[nb], 0, 0, 0);
        }
    }

    float* kvp = kvpart + (size_t)(bh * NT_ + stile) * D_ * D_;
#pragma unroll
    for (int nb = 0; nb < 4; ++nb) {
        const int e = nb * 16 + lx;
#pragma unroll
        for (int reg = 0; reg < 4; ++reg) {
            const int dd = w * 16 + gk * 4 + reg;
            kvp[dd * D_ + e] = kvacc[nb][reg];
        }
    }

    if (tid < 64) {
        float s = 0.f;
#pragma unroll
        for (int r8i = 0; r8i < 16; ++r8i) {
            const short8 v = *reinterpret_cast<const short8*>(&KnT[tid * 136 + r8i * 8]);
#pragma unroll
            for (int j = 0; j < 8; ++j) s += bf16_to_f32((unsigned short)v[j]);
        }
        kspart[(bh * NT_ + stile) * D_ + tid] = s;
    } else if (tid < 128) {
        const int e = tid - 64;
        float s = 0.f;
#pragma unroll
        for (int r8i = 0; r8i < 16; ++r8i) {
            const short8 v = *reinterpret_cast<const short8*>(&VT[e * 136 + r8i * 8]);
#pragma unroll
            for (int j = 0; j < 8; ++j) s += bf16_to_f32((unsigned short)v[j]);
        }
        vspart[(bh * NT_ + stile) * D_ + e] = s;
    }
}

// ---- reduceKV: grid (16 idx-chunks, 64 bh), coalesced ----------------------
__global__ __launch_bounds__(256)
void reduceKV(const float* __restrict__ kvpart, const float* __restrict__ kspart,
              const float* __restrict__ vspart, float* __restrict__ kv,
              float* __restrict__ ksum, float* __restrict__ vsum)
{
    const int bh = blockIdx.y;
    const int idx = blockIdx.x * 256 + threadIdx.x;
    float s = 0.f;
    for (int t = 0; t < NT_; ++t)
        s += kvpart[(size_t)(bh * NT_ + t) * (D_ * D_) + idx];
    kv[(size_t)bh * D_ * D_ + idx] = s;

    if (blockIdx.x == 0 && threadIdx.x < 2 * D_) {
        const int d = threadIdx.x & 63;
        const float* src = (threadIdx.x < D_) ? kspart : vspart;
        float* dstp = (threadIdx.x < D_) ? ksum : vsum;
        float a = 0.f;
        for (int t = 0; t < NT_; ++t) a += src[(bh * NT_ + t) * D_ + d];
        dstp[bh * D_ + d] = a;
    }
}

// ---- attnB: per (b,h,64-row tile), 4 threads/row (Qn pre-normalized) -------
__global__ __launch_bounds__(256)
void attnB(const unsigned short* __restrict__ qkv,
           const float* __restrict__ kv, const float* __restrict__ ksum,
           const float* __restrict__ vsum, const float* __restrict__ msum,
           float* __restrict__ out)
{
    __shared__ unsigned short Qs[64 * 72];  // [r][d], stride 72
    __shared__ float KVs[64 * 64];          // [d][e]
    __shared__ float ksum_s[64], vsum_s[64];

    const int tid = threadIdx.x;
    const int stile = blockIdx.x, h = blockIdx.y, b = blockIdx.z;
    const int col0 = h * D_;
    const int s0 = stile * 64;
    const int bh = b * H_ + h;

#pragma unroll
    for (int t = 0; t < 2; ++t) {
        const int i = t * 256 + tid;
        const int r = i >> 3, c8 = i & 7;
        *reinterpret_cast<short8*>(&Qs[r * 72 + c8 * 8]) =
            *reinterpret_cast<const short8*>(
                &qkv[(size_t)(b * S_ + s0 + r) * DM_ + col0 + c8 * 8]);
    }
    {
        const float4* src = reinterpret_cast<const float4*>(kv + (size_t)bh * D_ * D_);
        float4* dst = reinterpret_cast<float4*>(&KVs[0]);
#pragma unroll
        for (int t = 0; t < 4; ++t) dst[t * 256 + tid] = src[t * 256 + tid];
        if (tid < 64) ksum_s[tid] = ksum[bh * D_ + tid];
        else if (tid < 128) vsum_s[tid - 64] = vsum[bh * D_ + (tid - 64)];
    }
    __syncthreads();

    const int r = tid >> 2, q = tid & 3;
    const int srow = s0 + r;
    const float msumb = msum[b];

    float x[64];
#pragma unroll
    for (int v = 0; v < 8; ++v) {
        const short8 rv = *reinterpret_cast<const short8*>(&Qs[r * 72 + v * 8]);
#pragma unroll
        for (int j = 0; j < 8; ++j)
            x[v * 8 + j] = bf16_to_f32((unsigned short)rv[j]);
    }

    float acc[16] = {};
    float nrm = 0.f;
    const int e0 = q * 16;
#pragma unroll
    for (int d = 0; d < 64; ++d) {
        const float qd = x[d];
        nrm += qd * ksum_s[d];
#pragma unroll
        for (int c4 = 0; c4 < 4; ++c4) {
            const float4 kv4 = *reinterpret_cast<const float4*>(&KVs[d * 64 + e0 + c4 * 4]);
            acc[c4 * 4 + 0] += qd * kv4.x;
            acc[c4 * 4 + 1] += qd * kv4.y;
            acc[c4 * 4 + 2] += qd * kv4.z;
            acc[c4 * 4 + 3] += qd * kv4.w;
        }
    }

    const float denom = nrm + EPSF + msumb;
    const float dinv = 1.0f / denom;
#pragma unroll
    for (int c4 = 0; c4 < 4; ++c4) {
        float4 o;
        o.x = (acc[c4 * 4 + 0] + vsum_s[e0 + c4 * 4 + 0]) * dinv;
        o.y = (acc[c4 * 4 + 1] + vsum_s[e0 + c4 * 4 + 1]) * dinv;
        o.z = (acc[c4 * 4 + 2] + vsum_s[e0 + c4 * 4 + 2]) * dinv;
        o.w = (acc[c4 * 4 + 3] + vsum_s[e0 + c4 * 4 + 3]) * dinv;
        *reinterpret_cast<float4*>(
            &out[(size_t)(b * S_ + srow) * DM_ + col0 + e0 + c4 * 4]) = o;
    }
}

extern "C" void kernel_launch(void* const* d_in, const int* in_sizes, int n_in,
                              void* d_out, int out_size, void* d_ws, size_t ws_size,
                              hipStream_t stream) {
    const float* hidden = (const float*)d_in[0];
    const float* mask   = (const float*)d_in[1];
    const float* Wq     = (const float*)d_in[2];
    const float* bq     = (const float*)d_in[3];
    const float* Wk     = (const float*)d_in[4];
    const float* bk     = (const float*)d_in[5];
    const float* Wv     = (const float*)d_in[6];
    const float* bv     = (const float*)d_in[7];
    float* out = (float*)d_out;

    unsigned short* hb  = (unsigned short*)d_ws;                  // 16M shorts
    unsigned short* Wt  = hb + (size_t)B_ * S_ * DM_;             // 3M shorts
    unsigned short* qkv = Wt + (size_t)3 * DM_ * DM_;             // 48M shorts
    float* kvpart = (float*)(qkv + (size_t)3 * (B_ * S_) * DM_);
    float* kspart = kvpart + (size_t)B_ * H_ * NT_ * D_ * D_;
    float* vspart = kspart + (size_t)B_ * H_ * NT_ * D_;
    float* kvf    = vspart + (size_t)B_ * H_ * NT_ * D_;
    float* ksum   = kvf + (size_t)B_ * H_ * D_ * D_;
    float* vsum   = ksum + (size_t)B_ * H_ * D_;
    float* msum   = vsum + (size_t)B_ * H_ * D_;

    msum_kernel<<<B_, 256, 0, stream>>>(mask, msum);
    convH<<<(B_ * S_ * DM_) / (256 * 8), 256, 0, stream>>>(hidden, hb);
    transposeW<<<dim3(16, 16, 3), 256, 0, stream>>>(Wq, Wk, Wv, Wt);
    gemm_qkv<<<3072, 256, 0, stream>>>(hb, Wt, bq, bk, bv, mask, qkv);
    attnA<<<dim3(NT_, H_, B_), 256, 0, stream>>>(qkv, kvpart, kspart, vspart);
    reduceKV<<<dim3(16, 64), 256, 0, stream>>>(kvpart, kspart, vspart, kvf, ksum, vsum);
    attnB<<<dim3(S_ / 64, H_, B_), 256, 0, stream>>>(qkv, kvf, ksum, vsum, msum, out);
}

// Round 13
// 325.416 us; speedup vs baseline: 1.0846x; 1.0846x over previous
//
#include <hip/hip_runtime.h>
#include <hip/hip_bf16.h>

// CosineSelfAttention — bf16 MFMA version, v5.
// B=4, S=4096, DM=1024, H=16, D=64. Linear attention.
//
// v5 changes (vs v4):
//   * reduceKV emits kv TRANSPOSED bf16, XOR-swizzled ([e][slot^(e&7)]) +
//     ksum bf16 (for MFMA broadcast) + vsum f32
//   * attnB rewritten on MFMA: ctx = Qn@kv via 16x16x32, A-frags straight
//     from global (1 cache line per head-row), nrm via ksum-broadcast B-tile.
//     Kills the 4 GB aggregate LDS-read traffic of the VALU version.

#define B_  4
#define S_  4096
#define DM_ 1024
#define H_  16
#define D_  64
#define EPSF 1e-5f
#define NT_ 32   // 128-row s-tiles per (b,h) in attnA
#define BKG 64   // gemm k-step

typedef __attribute__((ext_vector_type(8))) short short8;
typedef __attribute__((ext_vector_type(4))) float f32x4;

__device__ inline unsigned short f32_to_bf16(float f) {
    unsigned int u = __builtin_bit_cast(unsigned int, f);
    u = (u + 0x7FFFu + ((u >> 16) & 1u)) >> 16;   // RNE
    return (unsigned short)u;
}
__device__ inline float bf16_to_f32(unsigned short u) {
    return __builtin_bit_cast(float, (unsigned int)u << 16);
}

__global__ __launch_bounds__(256)
void msum_kernel(const float* __restrict__ mask, float* __restrict__ msum) {
    const int b = blockIdx.x;
    float s = 0.f;
    for (int i = threadIdx.x; i < S_; i += 256)
        s += mask[b * S_ + i] / 10000.0f + 1.0f;
    for (int off = 32; off > 0; off >>= 1) s += __shfl_down(s, off);
    __shared__ float tmp[4];
    if ((threadIdx.x & 63) == 0) tmp[threadIdx.x >> 6] = s;
    __syncthreads();
    if (threadIdx.x == 0) msum[b] = tmp[0] + tmp[1] + tmp[2] + tmp[3];
}

// ---- hidden f32 -> bf16 ----------------------------------------------------
__global__ __launch_bounds__(256)
void convH(const float* __restrict__ h, unsigned short* __restrict__ hb) {
    const size_t i = ((size_t)blockIdx.x * 256 + threadIdx.x) * 8;
    const float4 a = *reinterpret_cast<const float4*>(h + i);
    const float4 c = *reinterpret_cast<const float4*>(h + i + 4);
    uint4 pk;
    pk.x = (unsigned int)f32_to_bf16(a.x) | ((unsigned int)f32_to_bf16(a.y) << 16);
    pk.y = (unsigned int)f32_to_bf16(a.z) | ((unsigned int)f32_to_bf16(a.w) << 16);
    pk.z = (unsigned int)f32_to_bf16(c.x) | ((unsigned int)f32_to_bf16(c.y) << 16);
    pk.w = (unsigned int)f32_to_bf16(c.z) | ((unsigned int)f32_to_bf16(c.w) << 16);
    *reinterpret_cast<uint4*>(hb + i) = pk;
}

// ---- Wt[n][k] = bf16(W[k][n]), per 64x64 tile ------------------------------
__global__ __launch_bounds__(256)
void transposeW(const float* __restrict__ Wq, const float* __restrict__ Wk,
                const float* __restrict__ Wv, unsigned short* __restrict__ Wt)
{
    __shared__ float T2[64 * 65];   // [nc][kr]
    const int tid = threadIdx.x;
    const int k0 = blockIdx.x * 64, n0 = blockIdx.y * 64, mi = blockIdx.z;
    const float* W = (mi == 0) ? Wq : (mi == 1) ? Wk : Wv;

#pragma unroll
    for (int t = 0; t < 4; ++t) {
        const int idx = t * 256 + tid;
        const int kr = idx >> 4, nc4 = idx & 15;
        const float4 v = *reinterpret_cast<const float4*>(
            &W[(size_t)(k0 + kr) * DM_ + n0 + nc4 * 4]);
        T2[(nc4 * 4 + 0) * 65 + kr] = v.x;
        T2[(nc4 * 4 + 1) * 65 + kr] = v.y;
        T2[(nc4 * 4 + 2) * 65 + kr] = v.z;
        T2[(nc4 * 4 + 3) * 65 + kr] = v.w;
    }
    __syncthreads();
#pragma unroll
    for (int t = 0; t < 4; ++t) {
        const int idx = t * 256 + tid;
        const int nr = idx >> 4, kc4 = idx & 15;
        unsigned int p0 = (unsigned int)f32_to_bf16(T2[nr * 65 + kc4 * 4 + 0]) |
                          ((unsigned int)f32_to_bf16(T2[nr * 65 + kc4 * 4 + 1]) << 16);
        unsigned int p1 = (unsigned int)f32_to_bf16(T2[nr * 65 + kc4 * 4 + 2]) |
                          ((unsigned int)f32_to_bf16(T2[nr * 65 + kc4 * 4 + 3]) << 16);
        uint2 pk; pk.x = p0; pk.y = p1;
        *reinterpret_cast<uint2*>(
            &Wt[(size_t)mi * DM_ * DM_ + (size_t)(n0 + nr) * DM_ + k0 + kc4 * 4]) = pk;
    }
}

// ---- qkv = {Qn, Kn, V}: GEMM + bias (+ mask + cosine-norm for Q,K) --------
__global__ __launch_bounds__(256)
void gemm_qkv(const unsigned short* __restrict__ hb, const unsigned short* __restrict__ Wt,
              const float* __restrict__ bq, const float* __restrict__ bk,
              const float* __restrict__ bv, const float* __restrict__ mask,
              unsigned short* __restrict__ qkv)
{
    __shared__ __align__(16) unsigned short As[128 * BKG];
    __shared__ __align__(16) unsigned short Bs[128 * BKG];

    const int tid = threadIdx.x;
    const int lane = tid & 63, w = tid >> 6;
    const int lx = lane & 15, gk = lane >> 4;
    const int wr = w >> 1, wc = w & 1;

    // T1: bijective XCD swizzle. 3072 blocks, 8 XCDs -> 384 contiguous each.
    const int wg = blockIdx.x;
    const int swz = (wg & 7) * 384 + (wg >> 3);
    const int mi = swz >> 10;            // 0..2
    const int rem = swz & 1023;
    const int mbase = (rem >> 3) * 128;
    const int nbase = (rem & 7) * 128;

    const float* bias = (mi == 0) ? bq : (mi == 1) ? bk : bv;
    const unsigned short* Wm = Wt + (size_t)mi * DM_ * DM_;
    unsigned short* outm = qkv + (size_t)mi * (B_ * S_) * DM_;

    const int srow = w * 32 + (lane >> 3);
    const int sslot = (lane & 7) ^ (lane >> 3);
    const unsigned short* aSrc = hb + (size_t)(mbase + srow) * DM_ + sslot * 8;
    const unsigned short* bSrc = Wm + (size_t)(nbase + srow) * DM_ + sslot * 8;

    f32x4 acc[4][4] = {};

    for (int kt = 0; kt < DM_ / BKG; ++kt) {
#pragma unroll
        for (int t = 0; t < 4; ++t) {
            __builtin_amdgcn_global_load_lds(
                (const __attribute__((address_space(1))) unsigned int*)(aSrc + kt * BKG + (size_t)t * 8 * DM_),
                (__attribute__((address_space(3))) unsigned int*)&As[(w * 32 + t * 8) * BKG],
                16, 0, 0);
            __builtin_amdgcn_global_load_lds(
                (const __attribute__((address_space(1))) unsigned int*)(bSrc + kt * BKG + (size_t)t * 8 * DM_),
                (__attribute__((address_space(3))) unsigned int*)&Bs[(w * 32 + t * 8) * BKG],
                16, 0, 0);
        }
        __syncthreads();

#pragma unroll
        for (int ks = 0; ks < 2; ++ks) {
            short8 a[4], bb[4];
#pragma unroll
            for (int f = 0; f < 4; ++f) {
                const int row = wr * 64 + f * 16 + lx;
                a[f] = *reinterpret_cast<const short8*>(
                    &As[row * BKG + (((ks * 4 + gk) ^ (lx & 7)) * 8)]);
            }
#pragma unroll
            for (int n = 0; n < 4; ++n) {
                const int row = wc * 64 + n * 16 + lx;
                bb[n] = *reinterpret_cast<const short8*>(
                    &Bs[row * BKG + (((ks * 4 + gk) ^ (lx & 7)) * 8)]);
            }
#pragma unroll
            for (int f = 0; f < 4; ++f)
#pragma unroll
                for (int n = 0; n < 4; ++n)
                    acc[f][n] = __builtin_amdgcn_mfma_f32_16x16x32_bf16(a[f], bb[n], acc[f][n], 0, 0, 0);
        }
        __syncthreads();
    }

    // epilogue: +bias; Q,K: *mask then row-normalize; -> bf16
    const int cole = nbase + wc * 64;
    float bias4[4];
#pragma unroll
    for (int n = 0; n < 4; ++n) bias4[n] = bias[cole + n * 16 + lx];

#pragma unroll
    for (int f = 0; f < 4; ++f) {
        const int rbase = mbase + wr * 64 + f * 16 + gk * 4;
        float y[4][4];
#pragma unroll
        for (int reg = 0; reg < 4; ++reg) {
            const float m = (mi == 2) ? 1.0f : (mask[rbase + reg] / 10000.0f + 1.0f);
            float ss = 0.f;
#pragma unroll
            for (int n = 0; n < 4; ++n) {
                const float v = (acc[f][n][reg] + bias4[n]) * m;
                y[reg][n] = v;
                ss += v * v;
            }
            if (mi != 2) {
                ss += __shfl_xor(ss, 1);
                ss += __shfl_xor(ss, 2);
                ss += __shfl_xor(ss, 4);
                ss += __shfl_xor(ss, 8);
                const float inv = 1.0f / (sqrtf(ss) + EPSF);
#pragma unroll
                for (int n = 0; n < 4; ++n) y[reg][n] *= inv;
            }
        }
#pragma unroll
        for (int n = 0; n < 4; ++n)
#pragma unroll
            for (int reg = 0; reg < 4; ++reg)
                outm[(size_t)(rbase + reg) * DM_ + cole + n * 16 + lx] =
                    f32_to_bf16(y[reg][n]);
    }
}

// ---- attnA: per (b,h,128-row tile): transpose -> kv += Kn^T V, sums --------
__global__ __launch_bounds__(256)
void attnA(const unsigned short* __restrict__ qkv,
           float* __restrict__ kvpart, float* __restrict__ kspart,
           float* __restrict__ vspart)
{
    __shared__ unsigned short KnT[64 * 136];  // [d][r], stride 136
    __shared__ unsigned short VT[64 * 136];   // [e][r]

    const int tid = threadIdx.x;
    const int lane = tid & 63, w = tid >> 6;
    const int lx = lane & 15, gk = lane >> 4;
    const int stile = blockIdx.x, h = blockIdx.y, b = blockIdx.z;
    const int col0 = h * D_;
    const int s0 = stile * 128;
    const int bh = b * H_ + h;

    const int rr = tid & 127;      // row within tile
    const int isV = tid >> 7;      // waves 0-1: Kn rows, waves 2-3: V rows
    const int srow = s0 + rr;

    const unsigned short* grow = qkv + (size_t)(1 + isV) * (B_ * S_) * DM_ +
                                 (size_t)(b * S_ + srow) * DM_ + col0;
    unsigned short* dst = isV ? VT : KnT;

    {
        short8 r8[8];
#pragma unroll
        for (int v = 0; v < 8; ++v)
            r8[v] = *reinterpret_cast<const short8*>(grow + v * 8);
#pragma unroll
        for (int v = 0; v < 8; ++v)
#pragma unroll
            for (int j = 0; j < 8; ++j)
                dst[(v * 8 + j) * 136 + rr] = (unsigned short)r8[v][j];
    }
    __syncthreads();

    f32x4 kvacc[4] = {};
#pragma unroll
    for (int kk = 0; kk < 4; ++kk) {
        const short8 af = *reinterpret_cast<const short8*>(
            &KnT[(w * 16 + lx) * 136 + kk * 32 + gk * 8]);
#pragma unroll
        for (int nb = 0; nb < 4; ++nb) {
            const short8 bf = *reinterpret_cast<const short8*>(
                &VT[(nb * 16 + lx) * 136 + kk * 32 + gk * 8]);
            kvacc[nb] = __builtin_amdgcn_mfma_f32_16x16x32_bf16(af, bf, kvacc[nb], 0, 0, 0);
        }
    }

    float* kvp = kvpart + (size_t)(bh * NT_ + stile) * D_ * D_;
#pragma unroll
    for (int nb = 0; nb < 4; ++nb) {
        const int e = nb * 16 + lx;
#pragma unroll
        for (int reg = 0; reg < 4; ++reg) {
            const int dd = w * 16 + gk * 4 + reg;
            kvp[dd * D_ + e] = kvacc[nb][reg];
        }
    }

    if (tid < 64) {
        float s = 0.f;
#pragma unroll
        for (int r8i = 0; r8i < 16; ++r8i) {
            const short8 v = *reinterpret_cast<const short8*>(&KnT[tid * 136 + r8i * 8]);
#pragma unroll
            for (int j = 0; j < 8; ++j) s += bf16_to_f32((unsigned short)v[j]);
        }
        kspart[(bh * NT_ + stile) * D_ + tid] = s;
    } else if (tid < 128) {
        const int e = tid - 64;
        float s = 0.f;
#pragma unroll
        for (int r8i = 0; r8i < 16; ++r8i) {
            const short8 v = *reinterpret_cast<const short8*>(&VT[e * 136 + r8i * 8]);
#pragma unroll
            for (int j = 0; j < 8; ++j) s += bf16_to_f32((unsigned short)v[j]);
        }
        vspart[(bh * NT_ + stile) * D_ + e] = s;
    }
}

// ---- reduceKV: sum partials -> kvT bf16 (transposed, XOR-swizzled) + sums --
__global__ __launch_bounds__(256)
void reduceKV(const float* __restrict__ kvpart, const float* __restrict__ kspart,
              const float* __restrict__ vspart, unsigned short* __restrict__ kvT,
              unsigned short* __restrict__ ksumb, float* __restrict__ vsum)
{
    const int bh = blockIdx.y;
    const int idx = blockIdx.x * 256 + threadIdx.x;   // = d*64 + e
    const int d = idx >> 6, e = idx & 63;
    float s = 0.f;
    for (int t = 0; t < NT_; ++t)
        s += kvpart[(size_t)(bh * NT_ + t) * (D_ * D_) + idx];
    // kvT[e][d], 16B-slot swizzled: slot = (d>>3) ^ (e&7)
    kvT[(size_t)bh * D_ * D_ + e * D_ + (((d >> 3) ^ (e & 7)) << 3) + (d & 7)] =
        f32_to_bf16(s);

    if (blockIdx.x == 0 && threadIdx.x < 2 * D_) {
        const int dd = threadIdx.x & 63;
        if (threadIdx.x < D_) {
            float a = 0.f;
            for (int t = 0; t < NT_; ++t) a += kspart[(bh * NT_ + t) * D_ + dd];
            ksumb[bh * D_ + dd] = f32_to_bf16(a);
        } else {
            float a = 0.f;
            for (int t = 0; t < NT_; ++t) a += vspart[(bh * NT_ + t) * D_ + dd];
            vsum[bh * D_ + dd] = a;
        }
    }
}

// ---- attnB: MFMA ctx = Qn@kv (+ nrm via ksum-broadcast tile) ---------------
__global__ __launch_bounds__(256)
void attnB(const unsigned short* __restrict__ qkv,
           const unsigned short* __restrict__ kvT,
           const unsigned short* __restrict__ ksumb,
           const float* __restrict__ vsum, const float* __restrict__ msum,
           float* __restrict__ out)
{
    __shared__ __align__(16) unsigned short kvTs[64 * 64];  // [e][slot^], 8 KB
    __shared__ __align__(16) unsigned short ksum_s[64];
    __shared__ float vsum_s[64];

    const int tid = threadIdx.x;
    const int lane = tid & 63, w = tid >> 6;
    const int lx = lane & 15, gk = lane >> 4;
    const int stile = blockIdx.x, h = blockIdx.y, b = blockIdx.z;
    const int col0 = h * D_;
    const int s0 = stile * 64;
    const int bh = b * H_ + h;

    // stage kvT (already swizzled in global -> linear copy), ksum, vsum
    {
        const short8* src = reinterpret_cast<const short8*>(kvT + (size_t)bh * D_ * D_);
        short8* dst = reinterpret_cast<short8*>(kvTs);
        dst[tid] = src[tid];
        dst[tid + 256] = src[tid + 256];
        if (tid < 8)
            reinterpret_cast<short8*>(ksum_s)[tid] =
                reinterpret_cast<const short8*>(ksumb + bh * D_)[tid];
        if (tid >= 64 && tid < 128) vsum_s[tid - 64] = vsum[bh * D_ + (tid - 64)];
    }
    __syncthreads();

    const float msumb = msum[b];
    // A-frags straight from global: lane lx owns Q row s0 + w*16 + lx
    const unsigned short* qrow = qkv + (size_t)(b * S_ + s0 + w * 16 + lx) * DM_ + col0;

    f32x4 acc[4] = {};
    f32x4 nacc = {};
#pragma unroll
    for (int ks = 0; ks < 2; ++ks) {
        const short8 a = *reinterpret_cast<const short8*>(qrow + ks * 32 + gk * 8);
#pragma unroll
        for (int n = 0; n < 4; ++n) {
            const short8 bb = *reinterpret_cast<const short8*>(
                &kvTs[(n * 16 + lx) * D_ + (((ks * 4 + gk) ^ (lx & 7)) << 3)]);
            acc[n] = __builtin_amdgcn_mfma_f32_16x16x32_bf16(a, bb, acc[n], 0, 0, 0);
        }
        // nrm tile: B = ksum broadcast to all 16 cols -> C[row][*] = nrm[row]
        const short8 kb = *reinterpret_cast<const short8*>(&ksum_s[ks * 32 + gk * 8]);
        nacc = __builtin_amdgcn_mfma_f32_16x16x32_bf16(a, kb, nacc, 0, 0, 0);
    }

    // epilogue: C layout col = lane&15, row = gk*4 + reg (within wave's 16 rows)
#pragma unroll
    for (int reg = 0; reg < 4; ++reg) {
        const int srow = s0 + w * 16 + gk * 4 + reg;
        const float dinv = 1.0f / (nacc[reg] + EPSF + msumb);
#pragma unroll
        for (int n = 0; n < 4; ++n) {
            out[(size_t)(b * S_ + srow) * DM_ + col0 + n * 16 + lx] =
                (acc[n][reg] + vsum_s[n * 16 + lx]) * dinv;
        }
    }
}

extern "C" void kernel_launch(void* const* d_in, const int* in_sizes, int n_in,
                              void* d_out, int out_size, void* d_ws, size_t ws_size,
                              hipStream_t stream) {
    const float* hidden = (const float*)d_in[0];
    const float* mask   = (const float*)d_in[1];
    const float* Wq     = (const float*)d_in[2];
    const float* bq     = (const float*)d_in[3];
    const float* Wk     = (const float*)d_in[4];
    const float* bk     = (const float*)d_in[5];
    const float* Wv     = (const float*)d_in[6];
    const float* bv     = (const float*)d_in[7];
    float* out = (float*)d_out;

    unsigned short* hb  = (unsigned short*)d_ws;                  // 16M shorts
    unsigned short* Wt  = hb + (size_t)B_ * S_ * DM_;             // 3M shorts
    unsigned short* qkv = Wt + (size_t)3 * DM_ * DM_;             // 48M shorts
    float* kvpart = (float*)(qkv + (size_t)3 * (B_ * S_) * DM_);  // B*H*NT*D*D f32
    float* kspart = kvpart + (size_t)B_ * H_ * NT_ * D_ * D_;
    float* vspart = kspart + (size_t)B_ * H_ * NT_ * D_;
    unsigned short* kvT   = (unsigned short*)(vspart + (size_t)B_ * H_ * NT_ * D_);
    unsigned short* ksumb = kvT + (size_t)B_ * H_ * D_ * D_;      // bf16
    float* vsum = (float*)(ksumb + (size_t)B_ * H_ * D_);         // 8KB-aligned ok
    float* msum = vsum + (size_t)B_ * H_ * D_;

    msum_kernel<<<B_, 256, 0, stream>>>(mask, msum);
    convH<<<(B_ * S_ * DM_) / (256 * 8), 256, 0, stream>>>(hidden, hb);
    transposeW<<<dim3(16, 16, 3), 256, 0, stream>>>(Wq, Wk, Wv, Wt);
    gemm_qkv<<<3072, 256, 0, stream>>>(hb, Wt, bq, bk, bv, mask, qkv);
    attnA<<<dim3(NT_, H_, B_), 256, 0, stream>>>(qkv, kvpart, kspart, vspart);
    reduceKV<<<dim3(16, 64), 256, 0, stream>>>(kvpart, kspart, vspart, kvT, ksumb, vsum);
    attnB<<<dim3(S_ / 64, H_, B_), 256, 0, stream>>>(qkv, kvT, ksumb, vsum, msum, out);
}